// Round 5
// baseline (373.108 us; speedup 1.0000x reference)
//
#include <hip/hip_runtime.h>
#include <hip/hip_bf16.h>

#define NBATCH 4
#define SEQ    2048
#define EMBED  1024
#define HEADS  16
#define HD     64

typedef __attribute__((ext_vector_type(8))) short bf16x8;
typedef __attribute__((ext_vector_type(4))) float f32x4;
typedef __attribute__((ext_vector_type(16))) float f32x16;

__device__ __forceinline__ short f2bf(float f) {
  union { float f; unsigned u; } v; v.f = f;
  unsigned r = v.u + 0x7fffu + ((v.u >> 16) & 1u);
  return (short)(r >> 16);
}

__device__ __forceinline__ unsigned pkbf(float a, float b) {
#if __has_builtin(__builtin_amdgcn_cvt_pk_bf16_f32)
  typedef __attribute__((ext_vector_type(2))) __bf16 bf16x2_t;
  bf16x2_t r = __builtin_amdgcn_cvt_pk_bf16_f32(a, b);
  union { bf16x2_t v; unsigned u; } cv; cv.v = r; return cv.u;
#else
  return (unsigned)(unsigned short)f2bf(a) | ((unsigned)(unsigned short)f2bf(b) << 16);
#endif
}

typedef __attribute__((address_space(1))) const void gas_void;
typedef __attribute__((address_space(3))) void las_void;
__device__ __forceinline__ void glds16(const void* g, void* l) {
  __builtin_amdgcn_global_load_lds((gas_void*)g, (las_void*)l, 16, 0, 0);
}

__device__ __forceinline__ bf16x8 mk8(unsigned a, unsigned b, unsigned c, unsigned d) {
  union { unsigned u[4]; bf16x8 v; } t;
  t.u[0] = a; t.u[1] = b; t.u[2] = c; t.u[3] = d; return t.v;
}

__device__ __forceinline__ void pl32swap(unsigned &a, unsigned &b) {
  asm volatile("v_permlane32_swap_b32 %0, %1" : "+v"(a), "+v"(b));
}

#define MFMA32(A, B, C) __builtin_amdgcn_mfma_f32_32x32x16_bf16((A), (B), (C), 0, 0, 0)

#define C2 0.04508422f  // log2(e) / sqrt(1024), folded into Wq at conversion

// ---------------- fused weight conversion (Wo + Wq*C2 + Wk + Wv) ----------------
__global__ __launch_bounds__(256) void cvt_all(
    const float* __restrict__ Wo, const float* __restrict__ Wq,
    const float* __restrict__ Wk, const float* __restrict__ Wv,
    short* __restrict__ dWo, short* __restrict__ dWq,
    short* __restrict__ dWk, short* __restrict__ dWv)
{
  int e = (blockIdx.x * 256 + threadIdx.x) * 4;
  const float* src; short* dst; int off; float sc = 1.0f;
  if (e < EMBED * EMBED) { src = Wo; dst = dWo; off = e; }
  else {
    int j = e - EMBED * EMBED;
    if      (j < 4096)  { src = Wq; dst = dWq; off = j; sc = C2; }
    else if (j < 8192)  { src = Wk; dst = dWk; off = j - 4096; }
    else if (j < 12288) { src = Wv; dst = dWv; off = j - 8192; }
    else return;
  }
  float4 v = *(const float4*)(src + off);
  ushort4 p;
  p.x = (unsigned short)f2bf(v.x * sc);
  p.y = (unsigned short)f2bf(v.y * sc);
  p.z = (unsigned short)f2bf(v.z * sc);
  p.w = (unsigned short)f2bf(v.w * sc);
  *(ushort4*)(dst + off) = p;
}

// ---------------- mask (int32 0/1) -> bitmask ----------------
__global__ __launch_bounds__(256) void mask_pack(const int* __restrict__ mask,
                                                 unsigned long long* __restrict__ bits) {
  long long t = (long long)blockIdx.x * 256 + threadIdx.x;
  int lane = threadIdx.x & 63;
  int m = mask[t];
  unsigned long long b = __ballot(m != 0);
  if (lane == 0) bits[t >> 6] = b;
}

// ---------------- QKV projection (unchanged from R4, passed) ----------------
__global__ __launch_bounds__(256) void proj_kernel(
    const float* __restrict__ srcQ, const float* __restrict__ srcK, const float* __restrict__ srcV,
    const short* __restrict__ WbQ, const short* __restrict__ WbK, const short* __restrict__ WbV,
    short* __restrict__ Qp, short* __restrict__ Kp, short* __restrict__ Vt)
{
  int rt = blockIdx.x;
  int h  = blockIdx.y;
  int mz = blockIdx.z;
  const float* src = (mz == 0) ? srcQ : ((mz == 1) ? srcK : srcV);
  const short* Wb  = (mz == 0) ? WbQ : ((mz == 1) ? WbK : WbV);

  __shared__ __align__(16) short At[64][72];

  int tid = threadIdx.x;
  int r0 = rt * 64;
  for (int idx = tid; idx < 64 * 16; idx += 256) {
    int row = idx >> 4;
    int c4  = idx & 15;
    float4 v = *(const float4*)(src + (long long)(r0 + row) * EMBED + h * HD + c4 * 4);
    uint2 pk2;
    pk2.x = pkbf(v.x, v.y);
    pk2.y = pkbf(v.z, v.w);
    *(uint2*)&At[row][c4 * 4] = pk2;
  }
  __syncthreads();

  int lane = tid & 63, w = tid >> 6, quad = lane >> 4, l15 = lane & 15;

  bf16x8 af0 = *(const bf16x8*)&At[w * 16 + l15][quad * 8];
  bf16x8 af1 = *(const bf16x8*)&At[w * 16 + l15][32 + quad * 8];

  f32x4 acc[4];
  for (int cg = 0; cg < 4; cg++) {
    acc[cg] = (f32x4){0.f, 0.f, 0.f, 0.f};
    bf16x8 b0 = *(const bf16x8*)(Wb + (cg * 16 + l15) * 64 + quad * 8);
    bf16x8 b1 = *(const bf16x8*)(Wb + (cg * 16 + l15) * 64 + 32 + quad * 8);
    acc[cg] = __builtin_amdgcn_mfma_f32_16x16x32_bf16(af0, b0, acc[cg], 0, 0, 0);
    acc[cg] = __builtin_amdgcn_mfma_f32_16x16x32_bf16(af1, b1, acc[cg], 0, 0, 0);
  }

  int rloc = w * 16 + quad * 4;
  __syncthreads();
  if (mz < 2) {
#pragma unroll
    for (int cg = 0; cg < 4; cg++)
#pragma unroll
      for (int reg = 0; reg < 4; reg++)
        At[rloc + reg][cg * 16 + l15] = f2bf(acc[cg][reg]);
  } else {
#pragma unroll
    for (int cg = 0; cg < 4; cg++)
#pragma unroll
      for (int reg = 0; reg < 4; reg++)
        At[cg * 16 + l15][rloc + reg] = f2bf(acc[cg][reg]);
  }
  __syncthreads();

  short* dst = (mz == 0) ? Qp : ((mz == 1) ? Kp : Vt);
  int row2 = tid >> 2, ch = tid & 3;
  const uint4* lp = (const uint4*)&At[row2][ch * 16];
  uint4 v0 = lp[0], v1 = lp[1];
  char* g;
  if (mz < 2) {
    int r = r0 + row2; int n = r >> 11, s = r & 2047;
    g = (char*)(dst + ((long long)(n * HEADS + h) * SEQ + s) * HD) + ch * 32;
  } else {
    int n = r0 >> 11, s0 = r0 & 2047;
    g = (char*)(dst + ((long long)(n * HEADS + h) * HD + row2) * SEQ + s0) + ch * 32;
  }
  *(uint4*)g = v0;
  *(uint4*)(g + 16) = v1;
}

// ---------------- flash attention: KVBLK=128, 16 iterations ----------------
// R5 theory: attn time is iteration-count-bound (R0 16w/CU 2bar/iter ~= R3 8w/CU
// 1bar/iter ~= 130us; FETCH -77% changed nothing). Halve the iterations:
// 128-key tiles, 32KB staged per iter (8 glds16/wave in flight), LDS 64KB
// double-buffered. Per 32-key group: 4 QK MFMA -> softmax -> 4 PV MFMA with
// pa0/pa1 reused across groups (lower reg pressure than R3's 4-pa form).
// K LDS: [128k][128B] rows, granule XOR (row&7) -- identical math to R3/R4.
// V LDS: [64d][256B] rows, 16-granule XOR (d&15): LDS granule g of row d holds
// true k-granule g^(d&15); stage pre-applies the same XOR on the global src.
#define SOFTMAX_KK(SV, MW, PAV0, PAV1) do {                                       \
    unsigned n0 = ((MW) >> sh4) & 0xFu;                                           \
    unsigned n1 = ((MW) >> (sh4 + 8)) & 0xFu;                                     \
    unsigned n2 = ((MW) >> (sh4 + 16)) & 0xFu;                                    \
    unsigned n3 = ((MW) >> (sh4 + 24)) & 0xFu;                                    \
    float p0  = __builtin_amdgcn_exp2f(SV[0]);   p0  = (n0 & 1u) ? p0  : 0.f;     \
    float p1  = __builtin_amdgcn_exp2f(SV[1]);   p1  = (n0 & 2u) ? p1  : 0.f;     \
    float p2  = __builtin_amdgcn_exp2f(SV[2]);   p2  = (n0 & 4u) ? p2  : 0.f;     \
    float p3  = __builtin_amdgcn_exp2f(SV[3]);   p3  = (n0 & 8u) ? p3  : 0.f;     \
    float p4  = __builtin_amdgcn_exp2f(SV[4]);   p4  = (n1 & 1u) ? p4  : 0.f;     \
    float p5  = __builtin_amdgcn_exp2f(SV[5]);   p5  = (n1 & 2u) ? p5  : 0.f;     \
    float p6  = __builtin_amdgcn_exp2f(SV[6]);   p6  = (n1 & 4u) ? p6  : 0.f;     \
    float p7  = __builtin_amdgcn_exp2f(SV[7]);   p7  = (n1 & 8u) ? p7  : 0.f;     \
    float p8  = __builtin_amdgcn_exp2f(SV[8]);   p8  = (n2 & 1u) ? p8  : 0.f;     \
    float p9  = __builtin_amdgcn_exp2f(SV[9]);   p9  = (n2 & 2u) ? p9  : 0.f;     \
    float p10 = __builtin_amdgcn_exp2f(SV[10]);  p10 = (n2 & 4u) ? p10 : 0.f;     \
    float p11 = __builtin_amdgcn_exp2f(SV[11]);  p11 = (n2 & 8u) ? p11 : 0.f;     \
    float p12 = __builtin_amdgcn_exp2f(SV[12]);  p12 = (n3 & 1u) ? p12 : 0.f;     \
    float p13 = __builtin_amdgcn_exp2f(SV[13]);  p13 = (n3 & 2u) ? p13 : 0.f;     \
    float p14 = __builtin_amdgcn_exp2f(SV[14]);  p14 = (n3 & 4u) ? p14 : 0.f;     \
    float p15 = __builtin_amdgcn_exp2f(SV[15]);  p15 = (n3 & 8u) ? p15 : 0.f;     \
    lsum += (((p0 + p1) + (p2 + p3)) + ((p4 + p5) + (p6 + p7)))                   \
          + (((p8 + p9) + (p10 + p11)) + ((p12 + p13) + (p14 + p15)));            \
    unsigned u0 = pkbf(p0, p1),   u1 = pkbf(p2, p3);                              \
    unsigned u2 = pkbf(p4, p5),   u3 = pkbf(p6, p7);                              \
    unsigned u4 = pkbf(p8, p9),   u5 = pkbf(p10, p11);                            \
    unsigned u6 = pkbf(p12, p13), u7 = pkbf(p14, p15);                            \
    pl32swap(u0, u2); pl32swap(u1, u3);                                           \
    pl32swap(u4, u6); pl32swap(u5, u7);                                           \
    PAV0 = mk8(u0, u1, u2, u3);                                                   \
    PAV1 = mk8(u4, u5, u6, u7);                                                   \
  } while (0)

// One 32-key group: QK^T (K rows G*32+l31) -> softmax -> PV (k-slots 2G, 2G+1)
#define GRP(G, MW) do {                                                           \
    const char* KG = bK + (G) * 4096;                                             \
    f32x16 s = {};                                                                \
    __builtin_amdgcn_s_setprio(1);                                                \
    s = MFMA32(*(const bf16x8*)(KG + a4_0), qf0, s);                              \
    s = MFMA32(*(const bf16x8*)(KG + a4_1), qf1, s);                              \
    s = MFMA32(*(const bf16x8*)(KG + a4_2), qf2, s);                              \
    s = MFMA32(*(const bf16x8*)(KG + a4_3), qf3, s);                              \
    __builtin_amdgcn_s_setprio(0);                                                \
    bf16x8 pa0, pa1;                                                              \
    SOFTMAX_KK(s, MW, pa0, pa1);                                                  \
    int vg = ((G) * 64) ^ vmx;                                                    \
    __builtin_amdgcn_s_setprio(1);                                                \
    O0 = MFMA32(*(const bf16x8*)(bV + vb0 + vg), pa0, O0);                        \
    O1 = MFMA32(*(const bf16x8*)(bV + vb0 + vg + 8192), pa0, O1);                 \
    O0 = MFMA32(*(const bf16x8*)(bV + vb1 + vg), pa1, O0);                        \
    O1 = MFMA32(*(const bf16x8*)(bV + vb1 + vg + 8192), pa1, O1);                 \
    __builtin_amdgcn_s_setprio(0);                                                \
  } while (0)

__global__ __launch_bounds__(256, 2) void attn_kernel(
    const short* __restrict__ Qp, const short* __restrict__ Kp, const short* __restrict__ Vt,
    const unsigned long long* __restrict__ mbits, short* __restrict__ AO)
{
  // XCD-clustering remap (bijective): L = hi*128 + qt*8 + lo; pair = hi*8+lo
  int L  = blockIdx.x;
  int qt = (L >> 3) & 15;
  int p_ = ((L >> 7) << 3) | (L & 7);
  int h  = p_ & 15;
  int nb = p_ >> 4;
  int q0 = qt * 128;

  __shared__ __align__(16) char ldsK[2 * 16384];  // K tile [128k][64d] per buf
  __shared__ __align__(16) char ldsV[2 * 16384];  // V^T tile [64d][128k] per buf

  int tid = threadIdx.x, lane = tid & 63, w = tid >> 6;
  int l31 = lane & 31, hi5 = lane >> 5;
  int g8 = lane & 7, r8 = lane >> 3;
  int pp = lane & 7;
  unsigned sh4 = (unsigned)(hi5 * 4);

  long long nh = (long long)(nb * HEADS + h);
  const char* Kb = (const char*)(Kp + nh * SEQ * HD);
  const char* Vb = (const char*)(Vt + nh * HD * SEQ);

  // K staging: wave w stages chunks {w,w+4,w+8,w+12}; chunk = 8 rows x 128B.
  int kgo = w * 1024 + r8 * 128 + ((g8 ^ r8) << 4);
  // V staging: chunk = 4 d-rows x 256B; lane l: d = 4w + 16i + (l>>4),
  // LDS granule l&15 holds true granule (l&15)^(d&15); d&15 = 4w+(l>>4) (<=15).
  int vd15 = 4 * w + (lane >> 4);
  int vgo = vd15 * 4096 + ((((lane & 15) ^ vd15)) << 4);
  int klo = w * 1024;

  // K fragment reads: row = G*32 + l31 (row&7 = l31&7 = pp), granule ((jd<<1)|hi5)^pp
  int a4_0 = l31 * 128 + ((((0 | hi5) ^ pp)) << 4);
  int a4_1 = l31 * 128 + ((((2 | hi5) ^ pp)) << 4);
  int a4_2 = l31 * 128 + ((((4 | hi5) ^ pp)) << 4);
  int a4_3 = l31 * 128 + ((((6 | hi5) ^ pp)) << 4);
  // V fragment reads: row d = l31 (O0) / l31+32 (O1, same granule, +8192);
  // granule = ((j<<1)|hi5) ^ (l31&15), split: low2 ^ (l31&3), high2 ^ (l31&12)
  int vb0 = l31 * 256 + (((0 | hi5) ^ (l31 & 3)) << 4);
  int vb1 = l31 * 256 + (((2 | hi5) ^ (l31 & 3)) << 4);
  int vmx = (l31 & 12) << 4;

  int qrow = q0 + w * 32 + l31;
  const short* Qb = Qp + (nh * SEQ + qrow) * HD + hi5 * 8;
  bf16x8 qf0 = *(const bf16x8*)(Qb);
  bf16x8 qf1 = *(const bf16x8*)(Qb + 16);
  bf16x8 qf2 = *(const bf16x8*)(Qb + 32);
  bf16x8 qf3 = *(const bf16x8*)(Qb + 48);

  const ulonglong2* mp2 = (const ulonglong2*)(mbits + ((long long)nb * SEQ + qrow) * 32);

  f32x16 O0 = {}, O1 = {};
  float lsum = 0.f;

  // prologue: stage tile 0 into buffer 0 (4 K-chunks + 4 V-chunks per wave)
  {
    char* dK = ldsK + klo; char* dV = ldsV + klo;
    const char* sK = Kb + kgo; const char* sV = Vb + vgo;
    glds16(sK,          dK);
    glds16(sK + 4096,   dK + 4096);
    glds16(sK + 8192,   dK + 8192);
    glds16(sK + 12288,  dK + 12288);
    glds16(sV,          dV);
    glds16(sV + 65536,  dV + 4096);
    glds16(sV + 131072, dV + 8192);
    glds16(sV + 196608, dV + 12288);
  }
  ulonglong2 mcur = mp2[0], mnxt;

  for (int kt = 0; kt < 16; kt++) {
    __syncthreads();  // vmcnt drain: buf[kt&1] complete; all waves done with buf[kt&1^1]
    const char* bK = ldsK + (kt & 1) * 16384;
    const char* bV = ldsV + (kt & 1) * 16384;
    if (kt < 15) {
      char* dK = ldsK + ((kt & 1) ^ 1) * 16384 + klo;
      char* dV = ldsV + ((kt & 1) ^ 1) * 16384 + klo;
      const char* sK = Kb + (kt + 1) * 16384 + kgo;
      const char* sV = Vb + (kt + 1) * 256 + vgo;
      glds16(sK,          dK);
      glds16(sK + 4096,   dK + 4096);
      glds16(sK + 8192,   dK + 8192);
      glds16(sK + 12288,  dK + 12288);
      glds16(sV,          dV);
      glds16(sV + 65536,  dV + 4096);
      glds16(sV + 131072, dV + 8192);
      glds16(sV + 196608, dV + 12288);
      mnxt = mp2[kt + 1];
    }
    unsigned mw0 = (unsigned)mcur.x, mw1 = (unsigned)(mcur.x >> 32);
    unsigned mw2 = (unsigned)mcur.y, mw3 = (unsigned)(mcur.y >> 32);
    GRP(0, mw0);
    GRP(1, mw1);
    GRP(2, mw2);
    GRP(3, mw3);
    mcur = mnxt;
  }

  // lanes l and l+32 hold complementary k-halves of the same q row
  lsum += __shfl_xor(lsum, 32);
  float inv = 1.f / lsum;

  short* aoRow = AO + ((long long)nb * SEQ + qrow) * EMBED + h * HD + hi5 * 4;
#pragma unroll
  for (int j = 0; j < 4; j++) {
    uint2 pk;
    pk.x = pkbf(O0[4 * j] * inv, O0[4 * j + 1] * inv);
    pk.y = pkbf(O0[4 * j + 2] * inv, O0[4 * j + 3] * inv);
    *(uint2*)(aoRow + j * 8) = pk;
    pk.x = pkbf(O1[4 * j] * inv, O1[4 * j + 1] * inv);
    pk.y = pkbf(O1[4 * j + 2] * inv, O1[4 * j + 3] * inv);
    *(uint2*)(aoRow + 32 + j * 8) = pk;
  }
}

// ---------------- output projection: 128x128 tile, BK=64, double-buffered ----------------
// R5: barrier -> prefetch kc+1 into buf^1 -> compute kc (attn-style). R4's
// single-buffered load->barrier->compute exposed the full L2 round trip per kc.
__global__ __launch_bounds__(512) void outproj_kernel(
    const short* __restrict__ AO, const short* __restrict__ Wob,
    const float* __restrict__ bo, float* __restrict__ out)
{
  int rt = blockIdx.x, ct = blockIdx.y;
  __shared__ __align__(16) short AtL[2][128 * 64];  // 2 x 16 KB
  __shared__ __align__(16) short BtL[2][128 * 64];  // 2 x 16 KB

  int tid = threadIdx.x, lane = tid & 63, w = tid >> 6, quad = lane >> 4, l15 = lane & 15;
  int r8b = tid >> 3, g8 = tid & 7;
  int swz = g8 ^ (r8b & 7);
  int s3 = l15 & 7;
  int o0 = (quad ^ s3) * 16;
  int o1 = ((quad + 4) ^ s3) * 16;

  int r0 = rt * 128, c0 = ct * 128;
  int wr = (w >> 1) * 32, wc = (w & 1) * 64;

  const char* Abase = (const char*)AO  + (long long)(r0 + r8b) * 2048 + swz * 16;
  const char* Bbase = (const char*)Wob + (long long)(c0 + r8b) * 2048 + swz * 16;
  unsigned lbase = (unsigned)tid * 16;

  f32x4 acc[2][4];
#pragma unroll
  for (int mi = 0; mi < 2; mi++)
#pragma unroll
    for (int ni = 0; ni < 4; ni++) acc[mi][ni] = (f32x4){0.f, 0.f, 0.f, 0.f};

  // prologue: stage kc=0 into buf 0
  glds16(Abase,               (char*)AtL[0] + lbase);
  glds16(Abase + 64LL * 2048, (char*)AtL[0] + lbase + 8192);
  glds16(Bbase,               (char*)BtL[0] + lbase);
  glds16(Bbase + 64LL * 2048, (char*)BtL[0] + lbase + 8192);

  for (int kc = 0; kc < 16; kc++) {
    __syncthreads();  // vmcnt drain: buf[kc&1] ready
    const char* AB = (const char*)AtL[kc & 1];
    const char* BB = (const char*)BtL[kc & 1];
    if (kc < 15) {
      char* dA = (char*)AtL[(kc & 1) ^ 1] + lbase;
      char* dB = (char*)BtL[(kc & 1) ^ 1] + lbase;
      glds16(Abase + (kc + 1) * 128,               dA);
      glds16(Abase + 64LL * 2048 + (kc + 1) * 128, dA + 8192);
      glds16(Bbase + (kc + 1) * 128,               dB);
      glds16(Bbase + 64LL * 2048 + (kc + 1) * 128, dB + 8192);
    }

    bf16x8 af[2][2];
#pragma unroll
    for (int mi = 0; mi < 2; mi++) {
      int r = wr + mi * 16 + l15;
      af[mi][0] = *(const bf16x8*)(AB + r * 128 + o0);
      af[mi][1] = *(const bf16x8*)(AB + r * 128 + o1);
    }
    __builtin_amdgcn_s_setprio(1);
#pragma unroll
    for (int ni = 0; ni < 4; ni++) {
      int r = wc + ni * 16 + l15;
      bf16x8 b0 = *(const bf16x8*)(BB + r * 128 + o0);
      bf16x8 b1 = *(const bf16x8*)(BB + r * 128 + o1);
#pragma unroll
      for (int mi = 0; mi < 2; mi++) {
        acc[mi][ni] = __builtin_amdgcn_mfma_f32_16x16x32_bf16(af[mi][0], b0, acc[mi][ni], 0, 0, 0);
        acc[mi][ni] = __builtin_amdgcn_mfma_f32_16x16x32_bf16(af[mi][1], b1, acc[mi][ni], 0, 0, 0);
      }
    }
    __builtin_amdgcn_s_setprio(0);
  }

#pragma unroll
  for (int ni = 0; ni < 4; ni++) {
    float b = bo[c0 + wc + ni * 16 + l15];
#pragma unroll
    for (int mi = 0; mi < 2; mi++)
#pragma unroll
      for (int reg = 0; reg < 4; reg++) {
        int r = r0 + wr + mi * 16 + quad * 4 + reg;
        out[(long long)r * EMBED + c0 + wc + ni * 16 + l15] = acc[mi][ni][reg] + b;
      }
  }
}

extern "C" void kernel_launch(void* const* d_in, const int* in_sizes, int n_in,
                              void* d_out, int out_size, void* d_ws, size_t ws_size,
                              hipStream_t stream) {
  const float* values  = (const float*)d_in[0];
  const float* queries = (const float*)d_in[1];
  const float* keys    = (const float*)d_in[2];
  const int*   mask    = (const int*)d_in[3];
  const float* Wv = (const float*)d_in[4];
  const float* Wk = (const float*)d_in[5];
  const float* Wq = (const float*)d_in[6];
  const float* Wo = (const float*)d_in[7];
  const float* bo = (const float*)d_in[8];
  float* out = (float*)d_out;

  char* ws = (char*)d_ws;
  size_t off = 0;
  const size_t PROJ_BYTES = (size_t)NBATCH * HEADS * SEQ * HD * 2;  // 16 MiB
  short* Qp = (short*)(ws + off); off += PROJ_BYTES;
  short* Kp = (short*)(ws + off); off += PROJ_BYTES;
  short* Vt = (short*)(ws + off); off += PROJ_BYTES;
  short* AO = (short*)(ws + off); off += PROJ_BYTES;
  unsigned long long* mbits = (unsigned long long*)(ws + off);
  off += (size_t)NBATCH * SEQ * (SEQ / 64) * 8;  // 2 MiB
  short* Wob = (short*)(ws + off); off += (size_t)EMBED * EMBED * 2;  // 2 MiB
  short* WbQ = (short*)(ws + off); off += HD * HD * 2;
  short* WbK = (short*)(ws + off); off += HD * HD * 2;
  short* WbV = (short*)(ws + off); off += HD * HD * 2;

  cvt_all<<<dim3((EMBED * EMBED + 3 * HD * HD) / 4 / 256), dim3(256), 0, stream>>>(
      Wo, Wq, Wk, Wv, Wob, WbQ, WbK, WbV);

  mask_pack<<<dim3((NBATCH * SEQ * SEQ) / 256), dim3(256), 0, stream>>>(mask, mbits);

  proj_kernel<<<dim3((NBATCH * SEQ) / 64, HEADS, 3), dim3(256), 0, stream>>>(
      queries, keys, values, WbQ, WbK, WbV, Qp, Kp, Vt);

  attn_kernel<<<dim3(SEQ / 128 * HEADS * NBATCH), dim3(256), 0, stream>>>(Qp, Kp, Vt, mbits, AO);

  outproj_kernel<<<dim3((NBATCH * SEQ) / 128, EMBED / 128), dim3(512), 0, stream>>>(AO, Wob, bo, out);
}

// Round 6
// 369.200 us; speedup vs baseline: 1.0106x; 1.0106x over previous
//
#include <hip/hip_runtime.h>
#include <hip/hip_bf16.h>

#define NBATCH 4
#define SEQ    2048
#define EMBED  1024
#define HEADS  16
#define HD     64

typedef __attribute__((ext_vector_type(8))) short bf16x8;
typedef __attribute__((ext_vector_type(4))) float f32x4;
typedef __attribute__((ext_vector_type(16))) float f32x16;

__device__ __forceinline__ short f2bf(float f) {
  union { float f; unsigned u; } v; v.f = f;
  unsigned r = v.u + 0x7fffu + ((v.u >> 16) & 1u);
  return (short)(r >> 16);
}

__device__ __forceinline__ unsigned pkbf(float a, float b) {
#if __has_builtin(__builtin_amdgcn_cvt_pk_bf16_f32)
  typedef __attribute__((ext_vector_type(2))) __bf16 bf16x2_t;
  bf16x2_t r = __builtin_amdgcn_cvt_pk_bf16_f32(a, b);
  union { bf16x2_t v; unsigned u; } cv; cv.v = r; return cv.u;
#else
  return (unsigned)(unsigned short)f2bf(a) | ((unsigned)(unsigned short)f2bf(b) << 16);
#endif
}

typedef __attribute__((address_space(1))) const void gas_void;
typedef __attribute__((address_space(3))) void las_void;
__device__ __forceinline__ void glds16(const void* g, void* l) {
  __builtin_amdgcn_global_load_lds((gas_void*)g, (las_void*)l, 16, 0, 0);
}

__device__ __forceinline__ bf16x8 mk8(unsigned a, unsigned b, unsigned c, unsigned d) {
  union { unsigned u[4]; bf16x8 v; } t;
  t.u[0] = a; t.u[1] = b; t.u[2] = c; t.u[3] = d; return t.v;
}

__device__ __forceinline__ void pl32swap(unsigned &a, unsigned &b) {
  asm volatile("v_permlane32_swap_b32 %0, %1" : "+v"(a), "+v"(b));
}

#define MFMA32(A, B, C) __builtin_amdgcn_mfma_f32_32x32x16_bf16((A), (B), (C), 0, 0, 0)

#define C2 0.04508422f  // log2(e) / sqrt(1024), folded into Wq at conversion

// ---------------- fused weight conversion (Wo + Wq*C2 + Wk + Wv) ----------------
__global__ __launch_bounds__(256) void cvt_all(
    const float* __restrict__ Wo, const float* __restrict__ Wq,
    const float* __restrict__ Wk, const float* __restrict__ Wv,
    short* __restrict__ dWo, short* __restrict__ dWq,
    short* __restrict__ dWk, short* __restrict__ dWv)
{
  int e = (blockIdx.x * 256 + threadIdx.x) * 4;
  const float* src; short* dst; int off; float sc = 1.0f;
  if (e < EMBED * EMBED) { src = Wo; dst = dWo; off = e; }
  else {
    int j = e - EMBED * EMBED;
    if      (j < 4096)  { src = Wq; dst = dWq; off = j; sc = C2; }
    else if (j < 8192)  { src = Wk; dst = dWk; off = j - 4096; }
    else if (j < 12288) { src = Wv; dst = dWv; off = j - 8192; }
    else return;
  }
  float4 v = *(const float4*)(src + off);
  ushort4 p;
  p.x = (unsigned short)f2bf(v.x * sc);
  p.y = (unsigned short)f2bf(v.y * sc);
  p.z = (unsigned short)f2bf(v.z * sc);
  p.w = (unsigned short)f2bf(v.w * sc);
  *(ushort4*)(dst + off) = p;
}

// ---------------- mask (int32 0/1) -> bitmask, 4 elems/thread ----------------
// R6: each thread handles 4 strided elements (4 coalesced dword loads, 4 ballots),
// lane 0 stores 4 consecutive u64 words as 2x ulonglong2. Grid halved twice.
__global__ __launch_bounds__(256) void mask_pack(const int* __restrict__ mask,
                                                 unsigned long long* __restrict__ bits) {
  long long base = (long long)blockIdx.x * 1024;
  int tid = threadIdx.x, lane = tid & 63, wv = tid >> 6;
  const int* p = mask + base + wv * 256 + lane;
  int m0 = p[0], m1 = p[64], m2 = p[128], m3 = p[192];
  unsigned long long b0 = __ballot(m0 != 0);
  unsigned long long b1 = __ballot(m1 != 0);
  unsigned long long b2 = __ballot(m2 != 0);
  unsigned long long b3 = __ballot(m3 != 0);
  if (lane == 0) {
    unsigned long long* d = bits + (base >> 6) + wv * 4;
    ulonglong2 w0; w0.x = b0; w0.y = b1;
    ulonglong2 w1; w1.x = b2; w1.y = b3;
    *(ulonglong2*)(d)     = w0;
    *(ulonglong2*)(d + 2) = w1;
  }
}

// ---------------- QKV projection (unchanged from R4, passed) ----------------
__global__ __launch_bounds__(256) void proj_kernel(
    const float* __restrict__ srcQ, const float* __restrict__ srcK, const float* __restrict__ srcV,
    const short* __restrict__ WbQ, const short* __restrict__ WbK, const short* __restrict__ WbV,
    short* __restrict__ Qp, short* __restrict__ Kp, short* __restrict__ Vt)
{
  int rt = blockIdx.x;
  int h  = blockIdx.y;
  int mz = blockIdx.z;
  const float* src = (mz == 0) ? srcQ : ((mz == 1) ? srcK : srcV);
  const short* Wb  = (mz == 0) ? WbQ : ((mz == 1) ? WbK : WbV);

  __shared__ __align__(16) short At[64][72];

  int tid = threadIdx.x;
  int r0 = rt * 64;
  for (int idx = tid; idx < 64 * 16; idx += 256) {
    int row = idx >> 4;
    int c4  = idx & 15;
    float4 v = *(const float4*)(src + (long long)(r0 + row) * EMBED + h * HD + c4 * 4);
    uint2 pk2;
    pk2.x = pkbf(v.x, v.y);
    pk2.y = pkbf(v.z, v.w);
    *(uint2*)&At[row][c4 * 4] = pk2;
  }
  __syncthreads();

  int lane = tid & 63, w = tid >> 6, quad = lane >> 4, l15 = lane & 15;

  bf16x8 af0 = *(const bf16x8*)&At[w * 16 + l15][quad * 8];
  bf16x8 af1 = *(const bf16x8*)&At[w * 16 + l15][32 + quad * 8];

  f32x4 acc[4];
  for (int cg = 0; cg < 4; cg++) {
    acc[cg] = (f32x4){0.f, 0.f, 0.f, 0.f};
    bf16x8 b0 = *(const bf16x8*)(Wb + (cg * 16 + l15) * 64 + quad * 8);
    bf16x8 b1 = *(const bf16x8*)(Wb + (cg * 16 + l15) * 64 + 32 + quad * 8);
    acc[cg] = __builtin_amdgcn_mfma_f32_16x16x32_bf16(af0, b0, acc[cg], 0, 0, 0);
    acc[cg] = __builtin_amdgcn_mfma_f32_16x16x32_bf16(af1, b1, acc[cg], 0, 0, 0);
  }

  int rloc = w * 16 + quad * 4;
  __syncthreads();
  if (mz < 2) {
#pragma unroll
    for (int cg = 0; cg < 4; cg++)
#pragma unroll
      for (int reg = 0; reg < 4; reg++)
        At[rloc + reg][cg * 16 + l15] = f2bf(acc[cg][reg]);
  } else {
#pragma unroll
    for (int cg = 0; cg < 4; cg++)
#pragma unroll
      for (int reg = 0; reg < 4; reg++)
        At[cg * 16 + l15][rloc + reg] = f2bf(acc[cg][reg]);
  }
  __syncthreads();

  short* dst = (mz == 0) ? Qp : ((mz == 1) ? Kp : Vt);
  int row2 = tid >> 2, ch = tid & 3;
  const uint4* lp = (const uint4*)&At[row2][ch * 16];
  uint4 v0 = lp[0], v1 = lp[1];
  char* g;
  if (mz < 2) {
    int r = r0 + row2; int n = r >> 11, s = r & 2047;
    g = (char*)(dst + ((long long)(n * HEADS + h) * SEQ + s) * HD) + ch * 32;
  } else {
    int n = r0 >> 11, s0 = r0 & 2047;
    g = (char*)(dst + ((long long)(n * HEADS + h) * HD + row2) * SEQ + s0) + ch * 32;
  }
  *(uint4*)g = v0;
  *(uint4*)(g + 16) = v1;
}

// ---------------- flash attention: R4 geometry (KVBLK=64), split dispatch ----------------
// R6: (a) revert to R4's proven KVBLK=64 / 32KB-LDS config (131us; R5's 128-key
// tiles were 138us); (b) grid split into two half-batch dispatches (~66us each)
// so any other kernel >66us surfaces in the next top-5 -- the 235us non-attn
// remainder has never been measured; (c) persistent-zero accumulator C (zc),
// opaque-pinned, removing per-GRP f32x16 zero-init movs.
#define SOFTMAX_KK(SV, MW, PAV0, PAV1) do {                                       \
    unsigned n0 = ((MW) >> sh4) & 0xFu;                                           \
    unsigned n1 = ((MW) >> (sh4 + 8)) & 0xFu;                                     \
    unsigned n2 = ((MW) >> (sh4 + 16)) & 0xFu;                                    \
    unsigned n3 = ((MW) >> (sh4 + 24)) & 0xFu;                                    \
    float p0  = __builtin_amdgcn_exp2f(SV[0]);   p0  = (n0 & 1u) ? p0  : 0.f;     \
    float p1  = __builtin_amdgcn_exp2f(SV[1]);   p1  = (n0 & 2u) ? p1  : 0.f;     \
    float p2  = __builtin_amdgcn_exp2f(SV[2]);   p2  = (n0 & 4u) ? p2  : 0.f;     \
    float p3  = __builtin_amdgcn_exp2f(SV[3]);   p3  = (n0 & 8u) ? p3  : 0.f;     \
    float p4  = __builtin_amdgcn_exp2f(SV[4]);   p4  = (n1 & 1u) ? p4  : 0.f;     \
    float p5  = __builtin_amdgcn_exp2f(SV[5]);   p5  = (n1 & 2u) ? p5  : 0.f;     \
    float p6  = __builtin_amdgcn_exp2f(SV[6]);   p6  = (n1 & 4u) ? p6  : 0.f;     \
    float p7  = __builtin_amdgcn_exp2f(SV[7]);   p7  = (n1 & 8u) ? p7  : 0.f;     \
    float p8  = __builtin_amdgcn_exp2f(SV[8]);   p8  = (n2 & 1u) ? p8  : 0.f;     \
    float p9  = __builtin_amdgcn_exp2f(SV[9]);   p9  = (n2 & 2u) ? p9  : 0.f;     \
    float p10 = __builtin_amdgcn_exp2f(SV[10]);  p10 = (n2 & 4u) ? p10 : 0.f;     \
    float p11 = __builtin_amdgcn_exp2f(SV[11]);  p11 = (n2 & 8u) ? p11 : 0.f;     \
    float p12 = __builtin_amdgcn_exp2f(SV[12]);  p12 = (n3 & 1u) ? p12 : 0.f;     \
    float p13 = __builtin_amdgcn_exp2f(SV[13]);  p13 = (n3 & 2u) ? p13 : 0.f;     \
    float p14 = __builtin_amdgcn_exp2f(SV[14]);  p14 = (n3 & 4u) ? p14 : 0.f;     \
    float p15 = __builtin_amdgcn_exp2f(SV[15]);  p15 = (n3 & 8u) ? p15 : 0.f;     \
    lsum += (((p0 + p1) + (p2 + p3)) + ((p4 + p5) + (p6 + p7)))                   \
          + (((p8 + p9) + (p10 + p11)) + ((p12 + p13) + (p14 + p15)));            \
    unsigned u0 = pkbf(p0, p1),   u1 = pkbf(p2, p3);                              \
    unsigned u2 = pkbf(p4, p5),   u3 = pkbf(p6, p7);                              \
    unsigned u4 = pkbf(p8, p9),   u5 = pkbf(p10, p11);                            \
    unsigned u6 = pkbf(p12, p13), u7 = pkbf(p14, p15);                            \
    pl32swap(u0, u2); pl32swap(u1, u3);                                           \
    pl32swap(u4, u6); pl32swap(u5, u7);                                           \
    PAV0 = mk8(u0, u1, u2, u3);                                                   \
    PAV1 = mk8(u4, u5, u6, u7);                                                   \
  } while (0)

#define ATTN_ITER(BUF, KT) do {                                                   \
    __syncthreads();                                                              \
    if ((KT) < 31) {                                                              \
      const char* ks_ = Kb + ((KT) + 1) * 8192 + kgo;                             \
      const char* vs_ = Vb + ((KT) + 1) * 128 + vgo;                              \
      char* kd_ = ldsK + (((BUF) ^ 1) * 8192) + klo;                              \
      char* vd_ = ldsV + (((BUF) ^ 1) * 8192) + klo;                              \
      glds16(ks_,          kd_);                                                  \
      glds16(ks_ + 4096,   kd_ + 4096);                                           \
      glds16(vs_,          vd_);                                                  \
      glds16(vs_ + 131072, vd_ + 4096);                                           \
      mnxt = mptr[(KT) + 1];                                                      \
    }                                                                             \
    unsigned mlo = (unsigned)mcur, mhiw = (unsigned)(mcur >> 32);                 \
    const char* KB_ = ldsK + (BUF) * 8192;                                        \
    const char* VB_ = ldsV + (BUF) * 8192;                                        \
    bf16x8 pa0, pa1, pa2, pa3;                                                    \
    {                                                                             \
      __builtin_amdgcn_s_setprio(1);                                              \
      f32x16 s = MFMA32(*(const bf16x8*)(KB_ + a4_0), qf0, zc);                   \
      s = MFMA32(*(const bf16x8*)(KB_ + a4_1), qf1, s);                           \
      s = MFMA32(*(const bf16x8*)(KB_ + a4_2), qf2, s);                           \
      s = MFMA32(*(const bf16x8*)(KB_ + a4_3), qf3, s);                           \
      __builtin_amdgcn_s_setprio(0);                                              \
      SOFTMAX_KK(s, mlo, pa0, pa1);                                               \
    }                                                                             \
    {                                                                             \
      __builtin_amdgcn_s_setprio(1);                                              \
      f32x16 s = MFMA32(*(const bf16x8*)(KB_ + 4096 + a4_0), qf0, zc);            \
      s = MFMA32(*(const bf16x8*)(KB_ + 4096 + a4_1), qf1, s);                    \
      s = MFMA32(*(const bf16x8*)(KB_ + 4096 + a4_2), qf2, s);                    \
      s = MFMA32(*(const bf16x8*)(KB_ + 4096 + a4_3), qf3, s);                    \
      __builtin_amdgcn_s_setprio(0);                                              \
      SOFTMAX_KK(s, mhiw, pa2, pa3);                                              \
    }                                                                             \
    __builtin_amdgcn_s_setprio(1);                                                \
    O0 = MFMA32(*(const bf16x8*)(VB_ + a4_0),        pa0, O0);                    \
    O1 = MFMA32(*(const bf16x8*)(VB_ + 4096 + a4_0), pa0, O1);                    \
    O0 = MFMA32(*(const bf16x8*)(VB_ + a4_1),        pa1, O0);                    \
    O1 = MFMA32(*(const bf16x8*)(VB_ + 4096 + a4_1), pa1, O1);                    \
    O0 = MFMA32(*(const bf16x8*)(VB_ + a4_2),        pa2, O0);                    \
    O1 = MFMA32(*(const bf16x8*)(VB_ + 4096 + a4_2), pa2, O1);                    \
    O0 = MFMA32(*(const bf16x8*)(VB_ + a4_3),        pa3, O0);                    \
    O1 = MFMA32(*(const bf16x8*)(VB_ + 4096 + a4_3), pa3, O1);                    \
    __builtin_amdgcn_s_setprio(0);                                                \
    mcur = mnxt;                                                                  \
  } while (0)

__global__ __launch_bounds__(256, 3) void attn_kernel(
    const short* __restrict__ Qp, const short* __restrict__ Kp, const short* __restrict__ Vt,
    const unsigned long long* __restrict__ mbits, short* __restrict__ AO, int nbase)
{
  // XCD-clustering remap over half-grid (512 blocks): L = hi*128 + qt*8 + lo
  int L  = blockIdx.x;
  int qt = (L >> 3) & 15;
  int p_ = ((L >> 7) << 3) | (L & 7);   // 0..31
  int h  = p_ & 15;
  int nb = nbase + (p_ >> 4);
  int q0 = qt * 128;

  __shared__ __align__(16) char ldsK[2 * 8192];   // K tile [64k][64d], 2B, XOR-swizzled
  __shared__ __align__(16) char ldsV[2 * 8192];   // V^T tile [64d][64k], 2B, XOR-swizzled

  int tid = threadIdx.x, lane = tid & 63, w = tid >> 6;
  int l31 = lane & 31, hi5 = lane >> 5;
  int g8 = lane & 7, r8 = lane >> 3;
  int pp = lane & 7;
  unsigned sh4 = (unsigned)(hi5 * 4);

  long long nh = (long long)(nb * HEADS + h);
  const char* Kb = (const char*)(Kp + nh * SEQ * HD);
  const char* Vb = (const char*)(Vt + nh * HD * SEQ);

  int kgo = (w * 8 + r8) * 128 + ((g8 ^ r8) << 4);
  int vgo = (w * 8 + r8) * 4096 + ((g8 ^ r8) << 4);
  int klo = w * 1024;

  int a4_0 = l31 * 128 + ((((0 | hi5) ^ pp)) << 4);
  int a4_1 = l31 * 128 + ((((2 | hi5) ^ pp)) << 4);
  int a4_2 = l31 * 128 + ((((4 | hi5) ^ pp)) << 4);
  int a4_3 = l31 * 128 + ((((6 | hi5) ^ pp)) << 4);

  int qrow = q0 + w * 32 + l31;
  const short* Qb = Qp + (nh * SEQ + qrow) * HD + hi5 * 8;
  bf16x8 qf0 = *(const bf16x8*)(Qb);
  bf16x8 qf1 = *(const bf16x8*)(Qb + 16);
  bf16x8 qf2 = *(const bf16x8*)(Qb + 32);
  bf16x8 qf3 = *(const bf16x8*)(Qb + 48);

  const unsigned long long* mptr = mbits + ((long long)nb * SEQ + qrow) * 32;

  // persistent zero accumulator input (16 VGPRs, pinned so it isn't re-materialized)
  f32x16 zc = {};
  asm volatile("" : "+v"(zc));

  f32x16 O0 = {}, O1 = {};
  float lsum = 0.f;

  glds16(Kb + kgo,          ldsK + klo);
  glds16(Kb + 4096 + kgo,   ldsK + 4096 + klo);
  glds16(Vb + vgo,          ldsV + klo);
  glds16(Vb + vgo + 131072, ldsV + 4096 + klo);
  unsigned long long mcur = mptr[0], mnxt = 0;

  for (int it = 0; it < 16; it++) {
    ATTN_ITER(0, it * 2);
    ATTN_ITER(1, it * 2 + 1);
  }

  lsum += __shfl_xor(lsum, 32);
  float inv = 1.f / lsum;

  short* aoRow = AO + ((long long)nb * SEQ + qrow) * EMBED + h * HD + hi5 * 4;
#pragma unroll
  for (int j = 0; j < 4; j++) {
    uint2 pk;
    pk.x = pkbf(O0[4 * j] * inv, O0[4 * j + 1] * inv);
    pk.y = pkbf(O0[4 * j + 2] * inv, O0[4 * j + 3] * inv);
    *(uint2*)(aoRow + j * 8) = pk;
    pk.x = pkbf(O1[4 * j] * inv, O1[4 * j + 1] * inv);
    pk.y = pkbf(O1[4 * j + 2] * inv, O1[4 * j + 3] * inv);
    *(uint2*)(aoRow + 32 + j * 8) = pk;
  }
}

// ---------------- output projection: 128x128 tile, BK=64, double-buffered ----------------
__global__ __launch_bounds__(512) void outproj_kernel(
    const short* __restrict__ AO, const short* __restrict__ Wob,
    const float* __restrict__ bo, float* __restrict__ out)
{
  int rt = blockIdx.x, ct = blockIdx.y;
  __shared__ __align__(16) short AtL[2][128 * 64];  // 2 x 16 KB
  __shared__ __align__(16) short BtL[2][128 * 64];  // 2 x 16 KB

  int tid = threadIdx.x, lane = tid & 63, w = tid >> 6, quad = lane >> 4, l15 = lane & 15;
  int r8b = tid >> 3, g8 = tid & 7;
  int swz = g8 ^ (r8b & 7);
  int s3 = l15 & 7;
  int o0 = (quad ^ s3) * 16;
  int o1 = ((quad + 4) ^ s3) * 16;

  int r0 = rt * 128, c0 = ct * 128;
  int wr = (w >> 1) * 32, wc = (w & 1) * 64;

  const char* Abase = (const char*)AO  + (long long)(r0 + r8b) * 2048 + swz * 16;
  const char* Bbase = (const char*)Wob + (long long)(c0 + r8b) * 2048 + swz * 16;
  unsigned lbase = (unsigned)tid * 16;

  f32x4 acc[2][4];
#pragma unroll
  for (int mi = 0; mi < 2; mi++)
#pragma unroll
    for (int ni = 0; ni < 4; ni++) acc[mi][ni] = (f32x4){0.f, 0.f, 0.f, 0.f};

  glds16(Abase,               (char*)AtL[0] + lbase);
  glds16(Abase + 64LL * 2048, (char*)AtL[0] + lbase + 8192);
  glds16(Bbase,               (char*)BtL[0] + lbase);
  glds16(Bbase + 64LL * 2048, (char*)BtL[0] + lbase + 8192);

  for (int kc = 0; kc < 16; kc++) {
    __syncthreads();
    const char* AB = (const char*)AtL[kc & 1];
    const char* BB = (const char*)BtL[kc & 1];
    if (kc < 15) {
      char* dA = (char*)AtL[(kc & 1) ^ 1] + lbase;
      char* dB = (char*)BtL[(kc & 1) ^ 1] + lbase;
      glds16(Abase + (kc + 1) * 128,               dA);
      glds16(Abase + 64LL * 2048 + (kc + 1) * 128, dA + 8192);
      glds16(Bbase + (kc + 1) * 128,               dB);
      glds16(Bbase + 64LL * 2048 + (kc + 1) * 128, dB + 8192);
    }

    bf16x8 af[2][2];
#pragma unroll
    for (int mi = 0; mi < 2; mi++) {
      int r = wr + mi * 16 + l15;
      af[mi][0] = *(const bf16x8*)(AB + r * 128 + o0);
      af[mi][1] = *(const bf16x8*)(AB + r * 128 + o1);
    }
    __builtin_amdgcn_s_setprio(1);
#pragma unroll
    for (int ni = 0; ni < 4; ni++) {
      int r = wc + ni * 16 + l15;
      bf16x8 b0 = *(const bf16x8*)(BB + r * 128 + o0);
      bf16x8 b1 = *(const bf16x8*)(BB + r * 128 + o1);
#pragma unroll
      for (int mi = 0; mi < 2; mi++) {
        acc[mi][ni] = __builtin_amdgcn_mfma_f32_16x16x32_bf16(af[mi][0], b0, acc[mi][ni], 0, 0, 0);
        acc[mi][ni] = __builtin_amdgcn_mfma_f32_16x16x32_bf16(af[mi][1], b1, acc[mi][ni], 0, 0, 0);
      }
    }
    __builtin_amdgcn_s_setprio(0);
  }

#pragma unroll
  for (int ni = 0; ni < 4; ni++) {
    float b = bo[c0 + wc + ni * 16 + l15];
#pragma unroll
    for (int mi = 0; mi < 2; mi++)
#pragma unroll
      for (int reg = 0; reg < 4; reg++) {
        int r = r0 + wr + mi * 16 + quad * 4 + reg;
        out[(long long)r * EMBED + c0 + wc + ni * 16 + l15] = acc[mi][ni][reg] + b;
      }
  }
}

extern "C" void kernel_launch(void* const* d_in, const int* in_sizes, int n_in,
                              void* d_out, int out_size, void* d_ws, size_t ws_size,
                              hipStream_t stream) {
  const float* values  = (const float*)d_in[0];
  const float* queries = (const float*)d_in[1];
  const float* keys    = (const float*)d_in[2];
  const int*   mask    = (const int*)d_in[3];
  const float* Wv = (const float*)d_in[4];
  const float* Wk = (const float*)d_in[5];
  const float* Wq = (const float*)d_in[6];
  const float* Wo = (const float*)d_in[7];
  const float* bo = (const float*)d_in[8];
  float* out = (float*)d_out;

  char* ws = (char*)d_ws;
  size_t off = 0;
  const size_t PROJ_BYTES = (size_t)NBATCH * HEADS * SEQ * HD * 2;  // 16 MiB
  short* Qp = (short*)(ws + off); off += PROJ_BYTES;
  short* Kp = (short*)(ws + off); off += PROJ_BYTES;
  short* Vt = (short*)(ws + off); off += PROJ_BYTES;
  short* AO = (short*)(ws + off); off += PROJ_BYTES;
  unsigned long long* mbits = (unsigned long long*)(ws + off);
  off += (size_t)NBATCH * SEQ * (SEQ / 64) * 8;  // 2 MiB
  short* Wob = (short*)(ws + off); off += (size_t)EMBED * EMBED * 2;  // 2 MiB
  short* WbQ = (short*)(ws + off); off += HD * HD * 2;
  short* WbK = (short*)(ws + off); off += HD * HD * 2;
  short* WbV = (short*)(ws + off); off += HD * HD * 2;

  cvt_all<<<dim3((EMBED * EMBED + 3 * HD * HD) / 4 / 256), dim3(256), 0, stream>>>(
      Wo, Wq, Wk, Wv, Wob, WbQ, WbK, WbV);

  mask_pack<<<dim3((NBATCH * SEQ * SEQ) / 1024), dim3(256), 0, stream>>>(mask, mbits);

  proj_kernel<<<dim3((NBATCH * SEQ) / 64, HEADS, 3), dim3(256), 0, stream>>>(
      queries, keys, values, WbQ, WbK, WbV, Qp, Kp, Vt);

  // split into two half-batch dispatches (~66us each): any other kernel >66us
  // will surface in the rocprof top-5 next round.
  attn_kernel<<<dim3(512), dim3(256), 0, stream>>>(Qp, Kp, Vt, mbits, AO, 0);
  attn_kernel<<<dim3(512), dim3(256), 0, stream>>>(Qp, Kp, Vt, mbits, AO, 2);

  outproj_kernel<<<dim3((NBATCH * SEQ) / 128, EMBED / 128), dim3(512), 0, stream>>>(AO, Wob, bo, out);
}

// Round 7
// 349.720 us; speedup vs baseline: 1.0669x; 1.0557x over previous
//
#include <hip/hip_runtime.h>
#include <hip/hip_bf16.h>

#define NBATCH 4
#define SEQ    2048
#define EMBED  1024
#define HEADS  16
#define HD     64

typedef __attribute__((ext_vector_type(8))) short bf16x8;
typedef __attribute__((ext_vector_type(4))) float f32x4;
typedef __attribute__((ext_vector_type(16))) float f32x16;

__device__ __forceinline__ short f2bf(float f) {
  union { float f; unsigned u; } v; v.f = f;
  unsigned r = v.u + 0x7fffu + ((v.u >> 16) & 1u);
  return (short)(r >> 16);
}

__device__ __forceinline__ unsigned pkbf(float a, float b) {
#if __has_builtin(__builtin_amdgcn_cvt_pk_bf16_f32)
  typedef __attribute__((ext_vector_type(2))) __bf16 bf16x2_t;
  bf16x2_t r = __builtin_amdgcn_cvt_pk_bf16_f32(a, b);
  union { bf16x2_t v; unsigned u; } cv; cv.v = r; return cv.u;
#else
  return (unsigned)(unsigned short)f2bf(a) | ((unsigned)(unsigned short)f2bf(b) << 16);
#endif
}

typedef __attribute__((address_space(1))) const void gas_void;
typedef __attribute__((address_space(3))) void las_void;
__device__ __forceinline__ void glds16(const void* g, void* l) {
  __builtin_amdgcn_global_load_lds((gas_void*)g, (las_void*)l, 16, 0, 0);
}

__device__ __forceinline__ bf16x8 mk8(unsigned a, unsigned b, unsigned c, unsigned d) {
  union { unsigned u[4]; bf16x8 v; } t;
  t.u[0] = a; t.u[1] = b; t.u[2] = c; t.u[3] = d; return t.v;
}

__device__ __forceinline__ void pl32swap(unsigned &a, unsigned &b) {
  asm volatile("v_permlane32_swap_b32 %0, %1" : "+v"(a), "+v"(b));
}

#define MFMA32(A, B, C) __builtin_amdgcn_mfma_f32_32x32x16_bf16((A), (B), (C), 0, 0, 0)

#define C2 0.04508422f  // log2(e) / sqrt(1024), folded into Wq at conversion

// ---------------- fused weight conversion (Wo + Wq*C2 + Wk + Wv) ----------------
__global__ __launch_bounds__(256) void cvt_all(
    const float* __restrict__ Wo, const float* __restrict__ Wq,
    const float* __restrict__ Wk, const float* __restrict__ Wv,
    short* __restrict__ dWo, short* __restrict__ dWq,
    short* __restrict__ dWk, short* __restrict__ dWv)
{
  int e = (blockIdx.x * 256 + threadIdx.x) * 4;
  const float* src; short* dst; int off; float sc = 1.0f;
  if (e < EMBED * EMBED) { src = Wo; dst = dWo; off = e; }
  else {
    int j = e - EMBED * EMBED;
    if      (j < 4096)  { src = Wq; dst = dWq; off = j; sc = C2; }
    else if (j < 8192)  { src = Wk; dst = dWk; off = j - 4096; }
    else if (j < 12288) { src = Wv; dst = dWv; off = j - 8192; }
    else return;
  }
  float4 v = *(const float4*)(src + off);
  ushort4 p;
  p.x = (unsigned short)f2bf(v.x * sc);
  p.y = (unsigned short)f2bf(v.y * sc);
  p.z = (unsigned short)f2bf(v.z * sc);
  p.w = (unsigned short)f2bf(v.w * sc);
  *(ushort4*)(dst + off) = p;
}

// ---------------- mask (int32 0/1) -> bitmask, 4 elems/thread (R6, kept) ----------------
__global__ __launch_bounds__(256) void mask_pack(const int* __restrict__ mask,
                                                 unsigned long long* __restrict__ bits) {
  long long base = (long long)blockIdx.x * 1024;
  int tid = threadIdx.x, lane = tid & 63, wv = tid >> 6;
  const int* p = mask + base + wv * 256 + lane;
  int m0 = p[0], m1 = p[64], m2 = p[128], m3 = p[192];
  unsigned long long b0 = __ballot(m0 != 0);
  unsigned long long b1 = __ballot(m1 != 0);
  unsigned long long b2 = __ballot(m2 != 0);
  unsigned long long b3 = __ballot(m3 != 0);
  if (lane == 0) {
    unsigned long long* d = bits + (base >> 6) + wv * 4;
    ulonglong2 w0; w0.x = b0; w0.y = b1;
    ulonglong2 w1; w1.x = b2; w1.y = b3;
    *(ulonglong2*)(d)     = w0;
    *(ulonglong2*)(d + 2) = w1;
  }
}

// ---------------- QKV projection (R4, passed) ----------------
__global__ __launch_bounds__(256) void proj_kernel(
    const float* __restrict__ srcQ, const float* __restrict__ srcK, const float* __restrict__ srcV,
    const short* __restrict__ WbQ, const short* __restrict__ WbK, const short* __restrict__ WbV,
    short* __restrict__ Qp, short* __restrict__ Kp, short* __restrict__ Vt)
{
  int rt = blockIdx.x;
  int h  = blockIdx.y;
  int mz = blockIdx.z;
  const float* src = (mz == 0) ? srcQ : ((mz == 1) ? srcK : srcV);
  const short* Wb  = (mz == 0) ? WbQ : ((mz == 1) ? WbK : WbV);

  __shared__ __align__(16) short At[64][72];

  int tid = threadIdx.x;
  int r0 = rt * 64;
  for (int idx = tid; idx < 64 * 16; idx += 256) {
    int row = idx >> 4;
    int c4  = idx & 15;
    float4 v = *(const float4*)(src + (long long)(r0 + row) * EMBED + h * HD + c4 * 4);
    uint2 pk2;
    pk2.x = pkbf(v.x, v.y);
    pk2.y = pkbf(v.z, v.w);
    *(uint2*)&At[row][c4 * 4] = pk2;
  }
  __syncthreads();

  int lane = tid & 63, w = tid >> 6, quad = lane >> 4, l15 = lane & 15;

  bf16x8 af0 = *(const bf16x8*)&At[w * 16 + l15][quad * 8];
  bf16x8 af1 = *(const bf16x8*)&At[w * 16 + l15][32 + quad * 8];

  f32x4 acc[4];
  for (int cg = 0; cg < 4; cg++) {
    acc[cg] = (f32x4){0.f, 0.f, 0.f, 0.f};
    bf16x8 b0 = *(const bf16x8*)(Wb + (cg * 16 + l15) * 64 + quad * 8);
    bf16x8 b1 = *(const bf16x8*)(Wb + (cg * 16 + l15) * 64 + 32 + quad * 8);
    acc[cg] = __builtin_amdgcn_mfma_f32_16x16x32_bf16(af0, b0, acc[cg], 0, 0, 0);
    acc[cg] = __builtin_amdgcn_mfma_f32_16x16x32_bf16(af1, b1, acc[cg], 0, 0, 0);
  }

  int rloc = w * 16 + quad * 4;
  __syncthreads();
  if (mz < 2) {
#pragma unroll
    for (int cg = 0; cg < 4; cg++)
#pragma unroll
      for (int reg = 0; reg < 4; reg++)
        At[rloc + reg][cg * 16 + l15] = f2bf(acc[cg][reg]);
  } else {
#pragma unroll
    for (int cg = 0; cg < 4; cg++)
#pragma unroll
      for (int reg = 0; reg < 4; reg++)
        At[cg * 16 + l15][rloc + reg] = f2bf(acc[cg][reg]);
  }
  __syncthreads();

  short* dst = (mz == 0) ? Qp : ((mz == 1) ? Kp : Vt);
  int row2 = tid >> 2, ch = tid & 3;
  const uint4* lp = (const uint4*)&At[row2][ch * 16];
  uint4 v0 = lp[0], v1 = lp[1];
  char* g;
  if (mz < 2) {
    int r = r0 + row2; int n = r >> 11, s = r & 2047;
    g = (char*)(dst + ((long long)(n * HEADS + h) * SEQ + s) * HD) + ch * 32;
  } else {
    int n = r0 >> 11, s0 = r0 & 2047;
    g = (char*)(dst + ((long long)(n * HEADS + h) * HD + row2) * SEQ + s0) + ch * 32;
  }
  *(uint4*)g = v0;
  *(uint4*)(g + 16) = v1;
}

// ---------------- flash attention: R4 body verbatim; R7 change = (256,4) ----------------
// R7 theory: R4's counters showed 25% occupancy (~2 resident blocks/CU) though
// VGPR(72)/LDS(32KB) allow 4. Latency-bound kernel + grid of exactly 4 blocks/CU
// -> forcing 4 waves/EU ((256,4), VGPR cap 128 >> 80 live set, no spill risk
// unlike R1's ~135-reg version) doubles overlap in a single scheduling round.
// Spill tripwire: WRITE_SIZE must stay 16.4 MB.
#define SOFTMAX_KK(SV, MW, PAV0, PAV1) do {                                       \
    unsigned n0 = ((MW) >> sh4) & 0xFu;                                           \
    unsigned n1 = ((MW) >> (sh4 + 8)) & 0xFu;                                     \
    unsigned n2 = ((MW) >> (sh4 + 16)) & 0xFu;                                    \
    unsigned n3 = ((MW) >> (sh4 + 24)) & 0xFu;                                    \
    float p0  = __builtin_amdgcn_exp2f(SV[0]);   p0  = (n0 & 1u) ? p0  : 0.f;     \
    float p1  = __builtin_amdgcn_exp2f(SV[1]);   p1  = (n0 & 2u) ? p1  : 0.f;     \
    float p2  = __builtin_amdgcn_exp2f(SV[2]);   p2  = (n0 & 4u) ? p2  : 0.f;     \
    float p3  = __builtin_amdgcn_exp2f(SV[3]);   p3  = (n0 & 8u) ? p3  : 0.f;     \
    float p4  = __builtin_amdgcn_exp2f(SV[4]);   p4  = (n1 & 1u) ? p4  : 0.f;     \
    float p5  = __builtin_amdgcn_exp2f(SV[5]);   p5  = (n1 & 2u) ? p5  : 0.f;     \
    float p6  = __builtin_amdgcn_exp2f(SV[6]);   p6  = (n1 & 4u) ? p6  : 0.f;     \
    float p7  = __builtin_amdgcn_exp2f(SV[7]);   p7  = (n1 & 8u) ? p7  : 0.f;     \
    float p8  = __builtin_amdgcn_exp2f(SV[8]);   p8  = (n2 & 1u) ? p8  : 0.f;     \
    float p9  = __builtin_amdgcn_exp2f(SV[9]);   p9  = (n2 & 2u) ? p9  : 0.f;     \
    float p10 = __builtin_amdgcn_exp2f(SV[10]);  p10 = (n2 & 4u) ? p10 : 0.f;     \
    float p11 = __builtin_amdgcn_exp2f(SV[11]);  p11 = (n2 & 8u) ? p11 : 0.f;     \
    float p12 = __builtin_amdgcn_exp2f(SV[12]);  p12 = (n3 & 1u) ? p12 : 0.f;     \
    float p13 = __builtin_amdgcn_exp2f(SV[13]);  p13 = (n3 & 2u) ? p13 : 0.f;     \
    float p14 = __builtin_amdgcn_exp2f(SV[14]);  p14 = (n3 & 4u) ? p14 : 0.f;     \
    float p15 = __builtin_amdgcn_exp2f(SV[15]);  p15 = (n3 & 8u) ? p15 : 0.f;     \
    lsum += (((p0 + p1) + (p2 + p3)) + ((p4 + p5) + (p6 + p7)))                   \
          + (((p8 + p9) + (p10 + p11)) + ((p12 + p13) + (p14 + p15)));            \
    unsigned u0 = pkbf(p0, p1),   u1 = pkbf(p2, p3);                              \
    unsigned u2 = pkbf(p4, p5),   u3 = pkbf(p6, p7);                              \
    unsigned u4 = pkbf(p8, p9),   u5 = pkbf(p10, p11);                            \
    unsigned u6 = pkbf(p12, p13), u7 = pkbf(p14, p15);                            \
    pl32swap(u0, u2); pl32swap(u1, u3);                                           \
    pl32swap(u4, u6); pl32swap(u5, u7);                                           \
    PAV0 = mk8(u0, u1, u2, u3);                                                   \
    PAV1 = mk8(u4, u5, u6, u7);                                                   \
  } while (0)

#define ATTN_ITER(BUF, KT) do {                                                   \
    __syncthreads();                                                              \
    if ((KT) < 31) {                                                              \
      const char* ks_ = Kb + ((KT) + 1) * 8192 + kgo;                             \
      const char* vs_ = Vb + ((KT) + 1) * 128 + vgo;                              \
      char* kd_ = ldsK + (((BUF) ^ 1) * 8192) + klo;                              \
      char* vd_ = ldsV + (((BUF) ^ 1) * 8192) + klo;                              \
      glds16(ks_,          kd_);                                                  \
      glds16(ks_ + 4096,   kd_ + 4096);                                           \
      glds16(vs_,          vd_);                                                  \
      glds16(vs_ + 131072, vd_ + 4096);                                           \
      mnxt = mptr[(KT) + 1];                                                      \
    }                                                                             \
    unsigned mlo = (unsigned)mcur, mhiw = (unsigned)(mcur >> 32);                 \
    const char* KB_ = ldsK + (BUF) * 8192;                                        \
    const char* VB_ = ldsV + (BUF) * 8192;                                        \
    bf16x8 pa0, pa1, pa2, pa3;                                                    \
    {                                                                             \
      f32x16 s = {};                                                              \
      __builtin_amdgcn_s_setprio(1);                                              \
      s = MFMA32(*(const bf16x8*)(KB_ + a4_0), qf0, s);                           \
      s = MFMA32(*(const bf16x8*)(KB_ + a4_1), qf1, s);                           \
      s = MFMA32(*(const bf16x8*)(KB_ + a4_2), qf2, s);                           \
      s = MFMA32(*(const bf16x8*)(KB_ + a4_3), qf3, s);                           \
      __builtin_amdgcn_s_setprio(0);                                              \
      SOFTMAX_KK(s, mlo, pa0, pa1);                                               \
    }                                                                             \
    {                                                                             \
      f32x16 s = {};                                                              \
      __builtin_amdgcn_s_setprio(1);                                              \
      s = MFMA32(*(const bf16x8*)(KB_ + 4096 + a4_0), qf0, s);                    \
      s = MFMA32(*(const bf16x8*)(KB_ + 4096 + a4_1), qf1, s);                    \
      s = MFMA32(*(const bf16x8*)(KB_ + 4096 + a4_2), qf2, s);                    \
      s = MFMA32(*(const bf16x8*)(KB_ + 4096 + a4_3), qf3, s);                    \
      __builtin_amdgcn_s_setprio(0);                                              \
      SOFTMAX_KK(s, mhiw, pa2, pa3);                                              \
    }                                                                             \
    __builtin_amdgcn_s_setprio(1);                                                \
    O0 = MFMA32(*(const bf16x8*)(VB_ + a4_0),        pa0, O0);                    \
    O1 = MFMA32(*(const bf16x8*)(VB_ + 4096 + a4_0), pa0, O1);                    \
    O0 = MFMA32(*(const bf16x8*)(VB_ + a4_1),        pa1, O0);                    \
    O1 = MFMA32(*(const bf16x8*)(VB_ + 4096 + a4_1), pa1, O1);                    \
    O0 = MFMA32(*(const bf16x8*)(VB_ + a4_2),        pa2, O0);                    \
    O1 = MFMA32(*(const bf16x8*)(VB_ + 4096 + a4_2), pa2, O1);                    \
    O0 = MFMA32(*(const bf16x8*)(VB_ + a4_3),        pa3, O0);                    \
    O1 = MFMA32(*(const bf16x8*)(VB_ + 4096 + a4_3), pa3, O1);                    \
    __builtin_amdgcn_s_setprio(0);                                                \
    mcur = mnxt;                                                                  \
  } while (0)

__global__ __launch_bounds__(256, 4) void attn_kernel(
    const short* __restrict__ Qp, const short* __restrict__ Kp, const short* __restrict__ Vt,
    const unsigned long long* __restrict__ mbits, short* __restrict__ AO)
{
  // XCD-clustering remap (bijective): L = hi*128 + qt*8 + lo; pair = hi*8+lo
  int L  = blockIdx.x;
  int qt = (L >> 3) & 15;
  int p_ = ((L >> 7) << 3) | (L & 7);
  int h  = p_ & 15;
  int nb = p_ >> 4;
  int q0 = qt * 128;

  __shared__ __align__(16) char ldsK[2 * 8192];   // K tile [64k][64d], 2B, XOR-swizzled
  __shared__ __align__(16) char ldsV[2 * 8192];   // V^T tile [64d][64k], 2B, XOR-swizzled

  int tid = threadIdx.x, lane = tid & 63, w = tid >> 6;
  int l31 = lane & 31, hi5 = lane >> 5;
  int g8 = lane & 7, r8 = lane >> 3;
  int pp = lane & 7;
  unsigned sh4 = (unsigned)(hi5 * 4);

  long long nh = (long long)(nb * HEADS + h);
  const char* Kb = (const char*)(Kp + nh * SEQ * HD);
  const char* Vb = (const char*)(Vt + nh * HD * SEQ);

  int kgo = (w * 8 + r8) * 128 + ((g8 ^ r8) << 4);
  int vgo = (w * 8 + r8) * 4096 + ((g8 ^ r8) << 4);
  int klo = w * 1024;

  int a4_0 = l31 * 128 + ((((0 | hi5) ^ pp)) << 4);
  int a4_1 = l31 * 128 + ((((2 | hi5) ^ pp)) << 4);
  int a4_2 = l31 * 128 + ((((4 | hi5) ^ pp)) << 4);
  int a4_3 = l31 * 128 + ((((6 | hi5) ^ pp)) << 4);

  int qrow = q0 + w * 32 + l31;
  const short* Qb = Qp + (nh * SEQ + qrow) * HD + hi5 * 8;
  bf16x8 qf0 = *(const bf16x8*)(Qb);
  bf16x8 qf1 = *(const bf16x8*)(Qb + 16);
  bf16x8 qf2 = *(const bf16x8*)(Qb + 32);
  bf16x8 qf3 = *(const bf16x8*)(Qb + 48);

  const unsigned long long* mptr = mbits + ((long long)nb * SEQ + qrow) * 32;

  f32x16 O0 = {}, O1 = {};
  float lsum = 0.f;

  glds16(Kb + kgo,          ldsK + klo);
  glds16(Kb + 4096 + kgo,   ldsK + 4096 + klo);
  glds16(Vb + vgo,          ldsV + klo);
  glds16(Vb + vgo + 131072, ldsV + 4096 + klo);
  unsigned long long mcur = mptr[0], mnxt = 0;

  for (int it = 0; it < 16; it++) {
    ATTN_ITER(0, it * 2);
    ATTN_ITER(1, it * 2 + 1);
  }

  lsum += __shfl_xor(lsum, 32);
  float inv = 1.f / lsum;

  short* aoRow = AO + ((long long)nb * SEQ + qrow) * EMBED + h * HD + hi5 * 4;
#pragma unroll
  for (int j = 0; j < 4; j++) {
    uint2 pk;
    pk.x = pkbf(O0[4 * j] * inv, O0[4 * j + 1] * inv);
    pk.y = pkbf(O0[4 * j + 2] * inv, O0[4 * j + 3] * inv);
    *(uint2*)(aoRow + j * 8) = pk;
    pk.x = pkbf(O1[4 * j] * inv, O1[4 * j + 1] * inv);
    pk.y = pkbf(O1[4 * j + 2] * inv, O1[4 * j + 3] * inv);
    *(uint2*)(aoRow + 32 + j * 8) = pk;
  }
}

// ---------------- output projection: 128x128 tile, BK=64, double-buffered (R5) ----------------
__global__ __launch_bounds__(512) void outproj_kernel(
    const short* __restrict__ AO, const short* __restrict__ Wob,
    const float* __restrict__ bo, float* __restrict__ out)
{
  int rt = blockIdx.x, ct = blockIdx.y;
  __shared__ __align__(16) short AtL[2][128 * 64];  // 2 x 16 KB
  __shared__ __align__(16) short BtL[2][128 * 64];  // 2 x 16 KB

  int tid = threadIdx.x, lane = tid & 63, w = tid >> 6, quad = lane >> 4, l15 = lane & 15;
  int r8b = tid >> 3, g8 = tid & 7;
  int swz = g8 ^ (r8b & 7);
  int s3 = l15 & 7;
  int o0 = (quad ^ s3) * 16;
  int o1 = ((quad + 4) ^ s3) * 16;

  int r0 = rt * 128, c0 = ct * 128;
  int wr = (w >> 1) * 32, wc = (w & 1) * 64;

  const char* Abase = (const char*)AO  + (long long)(r0 + r8b) * 2048 + swz * 16;
  const char* Bbase = (const char*)Wob + (long long)(c0 + r8b) * 2048 + swz * 16;
  unsigned lbase = (unsigned)tid * 16;

  f32x4 acc[2][4];
#pragma unroll
  for (int mi = 0; mi < 2; mi++)
#pragma unroll
    for (int ni = 0; ni < 4; ni++) acc[mi][ni] = (f32x4){0.f, 0.f, 0.f, 0.f};

  glds16(Abase,               (char*)AtL[0] + lbase);
  glds16(Abase + 64LL * 2048, (char*)AtL[0] + lbase + 8192);
  glds16(Bbase,               (char*)BtL[0] + lbase);
  glds16(Bbase + 64LL * 2048, (char*)BtL[0] + lbase + 8192);

  for (int kc = 0; kc < 16; kc++) {
    __syncthreads();
    const char* AB = (const char*)AtL[kc & 1];
    const char* BB = (const char*)BtL[kc & 1];
    if (kc < 15) {
      char* dA = (char*)AtL[(kc & 1) ^ 1] + lbase;
      char* dB = (char*)BtL[(kc & 1) ^ 1] + lbase;
      glds16(Abase + (kc + 1) * 128,               dA);
      glds16(Abase + 64LL * 2048 + (kc + 1) * 128, dA + 8192);
      glds16(Bbase + (kc + 1) * 128,               dB);
      glds16(Bbase + 64LL * 2048 + (kc + 1) * 128, dB + 8192);
    }

    bf16x8 af[2][2];
#pragma unroll
    for (int mi = 0; mi < 2; mi++) {
      int r = wr + mi * 16 + l15;
      af[mi][0] = *(const bf16x8*)(AB + r * 128 + o0);
      af[mi][1] = *(const bf16x8*)(AB + r * 128 + o1);
    }
    __builtin_amdgcn_s_setprio(1);
#pragma unroll
    for (int ni = 0; ni < 4; ni++) {
      int r = wc + ni * 16 + l15;
      bf16x8 b0 = *(const bf16x8*)(BB + r * 128 + o0);
      bf16x8 b1 = *(const bf16x8*)(BB + r * 128 + o1);
#pragma unroll
      for (int mi = 0; mi < 2; mi++) {
        acc[mi][ni] = __builtin_amdgcn_mfma_f32_16x16x32_bf16(af[mi][0], b0, acc[mi][ni], 0, 0, 0);
        acc[mi][ni] = __builtin_amdgcn_mfma_f32_16x16x32_bf16(af[mi][1], b1, acc[mi][ni], 0, 0, 0);
      }
    }
    __builtin_amdgcn_s_setprio(0);
  }

#pragma unroll
  for (int ni = 0; ni < 4; ni++) {
    float b = bo[c0 + wc + ni * 16 + l15];
#pragma unroll
    for (int mi = 0; mi < 2; mi++)
#pragma unroll
      for (int reg = 0; reg < 4; reg++) {
        int r = r0 + wr + mi * 16 + quad * 4 + reg;
        out[(long long)r * EMBED + c0 + wc + ni * 16 + l15] = acc[mi][ni][reg] + b;
      }
  }
}

extern "C" void kernel_launch(void* const* d_in, const int* in_sizes, int n_in,
                              void* d_out, int out_size, void* d_ws, size_t ws_size,
                              hipStream_t stream) {
  const float* values  = (const float*)d_in[0];
  const float* queries = (const float*)d_in[1];
  const float* keys    = (const float*)d_in[2];
  const int*   mask    = (const int*)d_in[3];
  const float* Wv = (const float*)d_in[4];
  const float* Wk = (const float*)d_in[5];
  const float* Wq = (const float*)d_in[6];
  const float* Wo = (const float*)d_in[7];
  const float* bo = (const float*)d_in[8];
  float* out = (float*)d_out;

  char* ws = (char*)d_ws;
  size_t off = 0;
  const size_t PROJ_BYTES = (size_t)NBATCH * HEADS * SEQ * HD * 2;  // 16 MiB
  short* Qp = (short*)(ws + off); off += PROJ_BYTES;
  short* Kp = (short*)(ws + off); off += PROJ_BYTES;
  short* Vt = (short*)(ws + off); off += PROJ_BYTES;
  short* AO = (short*)(ws + off); off += PROJ_BYTES;
  unsigned long long* mbits = (unsigned long long*)(ws + off);
  off += (size_t)NBATCH * SEQ * (SEQ / 64) * 8;  // 2 MiB
  short* Wob = (short*)(ws + off); off += (size_t)EMBED * EMBED * 2;  // 2 MiB
  short* WbQ = (short*)(ws + off); off += HD * HD * 2;
  short* WbK = (short*)(ws + off); off += HD * HD * 2;
  short* WbV = (short*)(ws + off); off += HD * HD * 2;

  cvt_all<<<dim3((EMBED * EMBED + 3 * HD * HD) / 4 / 256), dim3(256), 0, stream>>>(
      Wo, Wq, Wk, Wv, Wob, WbQ, WbK, WbV);

  mask_pack<<<dim3((NBATCH * SEQ * SEQ) / 1024), dim3(256), 0, stream>>>(mask, mbits);

  proj_kernel<<<dim3((NBATCH * SEQ) / 64, HEADS, 3), dim3(256), 0, stream>>>(
      queries, keys, values, WbQ, WbK, WbV, Qp, Kp, Vt);

  attn_kernel<<<dim3(SEQ / 128 * HEADS * NBATCH), dim3(256), 0, stream>>>(Qp, Kp, Vt, mbits, AO);

  outproj_kernel<<<dim3((NBATCH * SEQ) / 128, EMBED / 128), dim3(512), 0, stream>>>(AO, Wob, bo, out);
}